// Round 2
// baseline (27889.398 us; speedup 1.0000x reference)
//
#include <hip/hip_runtime.h>
#include <cstdint>
#include <cstddef>

#define NB   32
#define NS   512
#define EMBD 512
#define HID  1024
#define G4   4096
#define VOC  8192
#define MROWS (NS*NB)   // 16384

// ---------------- embedding gather: emb[m][e] = emb_W[e][tok(m)] + emb_b[e] ----------------
__global__ __launch_bounds__(256)
void embed_kernel(const int* __restrict__ x, const float* __restrict__ embW,
                  const float* __restrict__ embB, float* __restrict__ emb)
{
    int idx = blockIdx.x * 256 + threadIdx.x;      // over m*128 + e4
    int m  = idx >> 7;
    int e  = (idx & 127) << 2;
    int s = m >> 5, b = m & 31;                    // m = s*NB + b
    int tok = x[b * NS + s];                       // x is [B][S]
    float4 o;
    o.x = embW[(size_t)(e+0) * VOC + tok] + embB[e+0];
    o.y = embW[(size_t)(e+1) * VOC + tok] + embB[e+1];
    o.z = embW[(size_t)(e+2) * VOC + tok] + embB[e+2];
    o.w = embW[(size_t)(e+3) * VOC + tok] + embB[e+3];
    *(float4*)&emb[(size_t)m * EMBD + e] = o;
}

// ---------------- fp32 GEMM:  C[M][N] = A[M][K] @ B[N][K]^T (+bias0+bias1) ----------------
// BM=BN=128, BK=16, 256 threads, 8x8 per-thread tile, register prefetch.
// REMAP=1: output row m=(s*NB+b) is written to row (b*NS+s)  (for the classifier).
template<int REMAP>
__global__ __launch_bounds__(256)
void gemm_nt(const float* __restrict__ A, const float* __restrict__ B,
             const float* __restrict__ bias0, const float* __restrict__ bias1,
             float* __restrict__ C, int M, int N, int K)
{
    constexpr int BK = 16, LDP = 128 + 4;
    __shared__ float As[BK][LDP];
    __shared__ float Bs[BK][LDP];
    int tid = threadIdx.x;
    int m0 = blockIdx.y * 128;
    int n0 = blockIdx.x * 128;
    int tx = tid & 15, ty = tid >> 4;

    float acc[8][8];
    #pragma unroll
    for (int i = 0; i < 8; i++)
        #pragma unroll
        for (int j = 0; j < 8; j++) acc[i][j] = 0.f;

    int row_[2], kq_[2];
    #pragma unroll
    for (int it = 0; it < 2; ++it) {
        int fid = it * 256 + tid;
        row_[it] = fid >> 2;
        kq_[it]  = (fid & 3) << 2;
    }
    float4 rA[2], rB[2];
    #pragma unroll
    for (int it = 0; it < 2; ++it) {
        rA[it] = *(const float4*)&A[(size_t)(m0 + row_[it]) * K + kq_[it]];
        rB[it] = *(const float4*)&B[(size_t)(n0 + row_[it]) * K + kq_[it]];
    }
    int KT = K / BK;
    for (int kt = 0; kt < KT; ++kt) {
        __syncthreads();
        #pragma unroll
        for (int it = 0; it < 2; ++it) {
            As[kq_[it]+0][row_[it]] = rA[it].x;
            As[kq_[it]+1][row_[it]] = rA[it].y;
            As[kq_[it]+2][row_[it]] = rA[it].z;
            As[kq_[it]+3][row_[it]] = rA[it].w;
            Bs[kq_[it]+0][row_[it]] = rB[it].x;
            Bs[kq_[it]+1][row_[it]] = rB[it].y;
            Bs[kq_[it]+2][row_[it]] = rB[it].z;
            Bs[kq_[it]+3][row_[it]] = rB[it].w;
        }
        __syncthreads();
        if (kt + 1 < KT) {
            int k0 = (kt + 1) * BK;
            #pragma unroll
            for (int it = 0; it < 2; ++it) {
                rA[it] = *(const float4*)&A[(size_t)(m0 + row_[it]) * K + k0 + kq_[it]];
                rB[it] = *(const float4*)&B[(size_t)(n0 + row_[it]) * K + k0 + kq_[it]];
            }
        }
        #pragma unroll
        for (int k = 0; k < BK; ++k) {
            float4 a0 = *(const float4*)&As[k][ty*4];
            float4 a1 = *(const float4*)&As[k][64 + ty*4];
            float4 b0 = *(const float4*)&Bs[k][tx*4];
            float4 b1 = *(const float4*)&Bs[k][64 + tx*4];
            float av[8] = {a0.x,a0.y,a0.z,a0.w, a1.x,a1.y,a1.z,a1.w};
            float bv[8] = {b0.x,b0.y,b0.z,b0.w, b1.x,b1.y,b1.z,b1.w};
            #pragma unroll
            for (int i = 0; i < 8; i++)
                #pragma unroll
                for (int j = 0; j < 8; j++)
                    acc[i][j] += av[i] * bv[j];
        }
    }
    #pragma unroll
    for (int i = 0; i < 8; i++) {
        int mrow = m0 + ((i < 4) ? (ty*4 + i) : (64 + ty*4 + (i-4)));
        size_t orow = mrow;
        if (REMAP) { int s = mrow >> 5, b = mrow & 31; orow = (size_t)b * NS + s; }
        #pragma unroll
        for (int jh = 0; jh < 2; ++jh) {
            int ncol = n0 + jh*64 + tx*4;
            float4 v;
            v.x = acc[i][jh*4+0]; v.y = acc[i][jh*4+1];
            v.z = acc[i][jh*4+2]; v.w = acc[i][jh*4+3];
            if (bias0) { v.x += bias0[ncol+0]; v.y += bias0[ncol+1];
                         v.z += bias0[ncol+2]; v.w += bias0[ncol+3]; }
            if (bias1) { v.x += bias1[ncol+0]; v.y += bias1[ncol+1];
                         v.z += bias1[ncol+2]; v.w += bias1[ncol+3]; }
            *(float4*)&C[orow * N + ncol] = v;
        }
    }
}

// ---------------- one LSTM time-step, v2 ----------------
// Block: 4 j-cols x 4 gates (16 W rows, taken straight from Whh row-major) x 16 batches.
// Grid: 512 blocks = 256 j-blocks x 2 batch-halves. 512 threads.
// LDS: 16 W rows (64KB) + 16 h rows (64KB) = 128KB, float4-swizzled:
//   float4 #p of a row stored at slot kt*8 + ((k4^kt)&7), kt=p>>3, k4=p&7.
// Thread (gt,bt,kt): acc[4 gates][4 batches] over k in [kt*32, kt*32+32).
// kt-reduction: 5-round shfl_xor butterfly (lanes = bt-half*32 + kt).
// Thread gt's 4 gate-accs are exactly {i,f,g,o} of j = jb+gt -> inline epilogue.
__global__ __launch_bounds__(512)
void lstm_step(const float* __restrict__ pre,    // [NB][G4] at time t
               const float* __restrict__ hprev,  // [NB][HID]
               float* __restrict__ c,            // [NB][HID] in-place
               const float* __restrict__ Whh,    // [G4][HID] row-major (original layout)
               float* __restrict__ hout)         // [NB][HID] = hs[t]
{
    __shared__ float4 lds4[32 * 256];            // 32 rows x 256 float4 = 128KB

    int tid = threadIdx.x;
    int jb    = (blockIdx.x >> 1) * 4;           // j-base (4 j per block)
    int bbase = (blockIdx.x & 1) * 16;           // batch half

    // ---- stage: rows 0..15 = Whh rows g(row); rows 16..31 = hprev rows ----
    #pragma unroll
    for (int it = 0; it < 16; ++it) {
        int i   = it * 512 + tid;                // 0..8191
        int row = i >> 8;                        // 0..31
        int p   = i & 255;                       // float4 index within row
        int kt  = p >> 3, k4 = p & 7;
        float4 v;
        if (row < 16) {
            int g = (row & 3) * 1024 + jb + (row >> 2);   // q = row&3, jj = row>>2
            v = *(const float4*)&Whh[(size_t)g * HID + p * 4];
        } else {
            int b = bbase + (row - 16);
            v = *(const float4*)&hprev[(size_t)b * HID + p * 4];
        }
        lds4[row * 256 + kt * 8 + ((k4 ^ kt) & 7)] = v;
    }
    __syncthreads();

    int gt = tid >> 7;          // 0..3  (j slot)
    int bt = (tid >> 5) & 3;    // 0..3  (batch quad)
    int kt = tid & 31;          // 0..31 (k chunk of 32 floats)

    float acc[4][4];
    #pragma unroll
    for (int q = 0; q < 4; q++)
        #pragma unroll
        for (int bb = 0; bb < 4; bb++) acc[q][bb] = 0.f;

    #pragma unroll
    for (int k4 = 0; k4 < 8; ++k4) {
        int slot = kt * 8 + ((k4 ^ kt) & 7);
        float4 w[4], h[4];
        #pragma unroll
        for (int q = 0; q < 4; q++)
            w[q] = lds4[(gt * 4 + q) * 256 + slot];       // row = jj*4+q
        #pragma unroll
        for (int bb = 0; bb < 4; bb++)
            h[bb] = lds4[(16 + bt * 4 + bb) * 256 + slot];
        #pragma unroll
        for (int q = 0; q < 4; q++)
            #pragma unroll
            for (int bb = 0; bb < 4; bb++)
                acc[q][bb] += w[q].x*h[bb].x + w[q].y*h[bb].y
                            + w[q].z*h[bb].z + w[q].w*h[bb].w;
    }

    // ---- reduce over kt (32 lanes within each wave-half) ----
    #pragma unroll
    for (int off = 1; off <= 16; off <<= 1) {
        #pragma unroll
        for (int q = 0; q < 4; q++)
            #pragma unroll
            for (int bb = 0; bb < 4; bb++)
                acc[q][bb] += __shfl_xor(acc[q][bb], off);
    }

    // ---- epilogue: lanes with kt==0; this thread's 4 accs = i,f,g,o of j=jb+gt ----
    if (kt == 0) {
        int j = jb + gt;
        #pragma unroll
        for (int bb = 0; bb < 4; bb++) {
            int b = bbase + bt * 4 + bb;
            float gi = acc[0][bb] + pre[(size_t)b * G4 + 0*1024 + j];
            float gf = acc[1][bb] + pre[(size_t)b * G4 + 1*1024 + j];
            float gg = acc[2][bb] + pre[(size_t)b * G4 + 2*1024 + j];
            float go = acc[3][bb] + pre[(size_t)b * G4 + 3*1024 + j];
            float iv = 1.f / (1.f + expf(-gi));
            float fv = 1.f / (1.f + expf(-gf));
            float gv = tanhf(gg);
            float ov = 1.f / (1.f + expf(-go));
            float cc = c[(size_t)b * HID + j];
            float cn = fv * cc + iv * gv;
            c[(size_t)b * HID + j]    = cn;
            hout[(size_t)b * HID + j] = ov * tanhf(cn);
        }
    }
}

extern "C" void kernel_launch(void* const* d_in, const int* in_sizes, int n_in,
                              void* d_out, int out_size, void* d_ws, size_t ws_size,
                              hipStream_t stream)
{
    const int*   x    = (const int*)  d_in[0];
    const float* embW = (const float*)d_in[1];
    const float* embB = (const float*)d_in[2];
    const float* Wih0 = (const float*)d_in[3];
    const float* Whh0 = (const float*)d_in[4];
    const float* bih0 = (const float*)d_in[5];
    const float* bhh0 = (const float*)d_in[6];
    const float* Wih1 = (const float*)d_in[7];
    const float* Whh1 = (const float*)d_in[8];
    const float* bih1 = (const float*)d_in[9];
    const float* bhh1 = (const float*)d_in[10];
    const float* clsW = (const float*)d_in[11];
    const float* clsB = (const float*)d_in[12];
    float* out = (float*)d_out;

    float* ws   = (float*)d_ws;
    float* emb  = ws;                          // 16384*512
    float* pre  = emb + (size_t)MROWS*EMBD;    // 16384*4096 (reused for pre0 then pre1)
    float* hs0  = pre + (size_t)MROWS*G4;      // 16384*1024
    float* hs1  = hs0 + (size_t)MROWS*HID;     // 16384*1024
    float* c0   = hs1 + (size_t)MROWS*HID;     // 32*1024
    float* c1   = c0 + (size_t)NB*HID;         // 32*1024
    float* zbuf = c1 + (size_t)NB*HID;         // 32*1024

    // zero c0, c1, zbuf (contiguous)
    hipMemsetAsync(c0, 0, (size_t)3 * NB * HID * sizeof(float), stream);

    embed_kernel<<<8192, 256, 0, stream>>>(x, embW, embB, emb);

    // pre0 = emb @ Wih0^T + bih0 + bhh0
    gemm_nt<0><<<dim3(G4/128, MROWS/128), 256, 0, stream>>>(emb, Wih0, bih0, bhh0, pre, MROWS, G4, EMBD);
    for (int t = 0; t < NS; ++t) {
        lstm_step<<<512, 512, 0, stream>>>(pre + (size_t)t*NB*G4,
                                           t ? hs0 + (size_t)(t-1)*NB*HID : zbuf,
                                           c0, Whh0, hs0 + (size_t)t*NB*HID);
    }
    // pre1 = hs0 @ Wih1^T + bih1 + bhh1
    gemm_nt<0><<<dim3(G4/128, MROWS/128), 256, 0, stream>>>(hs0, Wih1, bih1, bhh1, pre, MROWS, G4, HID);
    for (int t = 0; t < NS; ++t) {
        lstm_step<<<512, 512, 0, stream>>>(pre + (size_t)t*NB*G4,
                                           t ? hs1 + (size_t)(t-1)*NB*HID : zbuf,
                                           c1, Whh1, hs1 + (size_t)t*NB*HID);
    }
    // logits[b][s][v] = hs1[s*NB+b] @ cls_W^T + cls_b   (REMAP=1 writes row b*NS+s)
    gemm_nt<1><<<dim3(VOC/128, MROWS/128), 256, 0, stream>>>(hs1, clsW, clsB, nullptr, out, MROWS, VOC, HID);
}

// Round 3
// 21897.437 us; speedup vs baseline: 1.2736x; 1.2736x over previous
//
#include <hip/hip_runtime.h>
#include <cstdint>
#include <cstddef>

#define NB   32
#define NS   512
#define EMBD 512
#define HID  1024
#define G4   4096
#define VOC  8192
#define MROWS (NS*NB)   // 16384

typedef float f32x4 __attribute__((ext_vector_type(4)));
typedef short short8 __attribute__((ext_vector_type(8)));
typedef unsigned short ushort_t;

// ---------- bf16 helpers (RNE) ----------
__device__ __forceinline__ float bf2f(ushort_t u){
    union{unsigned int i; float f;} v; v.i = ((unsigned int)u) << 16; return v.f;
}
__device__ __forceinline__ ushort_t f2bf(float x){
    union{float f; unsigned int i;} v; v.f = x;
    unsigned int r = (v.i + 0x7FFFu + ((v.i >> 16) & 1u)) >> 16;
    return (ushort_t)r;
}
__device__ __forceinline__ void split2(float x, ushort_t& h, ushort_t& l){
    h = f2bf(x); l = f2bf(x - bf2f(h));
}
__device__ __forceinline__ float sigm(float x){ return 1.f / (1.f + expf(-x)); }

// ---------- weight split (+ optional gate-interleave permute: dst row g'=j*4+q <- src row q*1024+j) ----------
template<int PERM>
__global__ __launch_bounds__(256)
void wsplit(const float* __restrict__ src, ushort_t* __restrict__ hi,
            ushort_t* __restrict__ lo, int C)
{
    int i = blockIdx.x * 256 + threadIdx.x;
    int r = i / C, c = i - r * C;
    int sr = PERM ? ((r & 3) * 1024 + (r >> 2)) : r;
    float v = src[(size_t)sr * C + c];
    ushort_t h, l; split2(v, h, l);
    hi[i] = h; lo[i] = l;
}

// ---------- bias prep: bsum*(g') = bih[g]+bhh[g], g=(g'&3)*1024+(g'>>2) ----------
__global__ __launch_bounds__(256)
void bias_prep(const float* bih0, const float* bhh0, const float* bih1, const float* bhh1,
               float* bsum0p, float* bsum1p)
{
    int gp = blockIdx.x * 256 + threadIdx.x;   // 0..4095
    int g = (gp & 3) * 1024 + (gp >> 2);
    bsum0p[gp] = bih0[g] + bhh0[g];
    bsum1p[gp] = bih1[g] + bhh1[g];
}

// ---------- embedding gather + split ----------
__global__ __launch_bounds__(256)
void embed_split(const int* __restrict__ x, const float* __restrict__ embW,
                 const float* __restrict__ embB, ushort_t* __restrict__ ehi,
                 ushort_t* __restrict__ elo)
{
    int idx = blockIdx.x * 256 + threadIdx.x;  // over MROWS*128
    int m = idx >> 7;
    int e = (idx & 127) << 2;
    int s = m >> 5, b = m & 31;                // m = s*NB+b
    int tok = x[b * NS + s];
    #pragma unroll
    for (int q = 0; q < 4; ++q) {
        float v = embW[(size_t)(e + q) * VOC + tok] + embB[e + q];
        ushort_t h, l; split2(v, h, l);
        ehi[(size_t)m * EMBD + e + q] = h;
        elo[(size_t)m * EMBD + e + q] = l;
    }
}

// ---------- bf16x3 MFMA accumulate helper: 3 product chains over NK k-steps of 32 ----------
template<int NK>
__device__ __forceinline__ void mm3(const ushort_t* __restrict__ Arh, const ushort_t* __restrict__ Arl,
                                    const ushort_t* __restrict__ Brh, const ushort_t* __restrict__ Brl,
                                    int ko, f32x4& a0, f32x4& a1, f32x4& a2)
{
    #pragma unroll 4
    for (int kk = 0; kk < NK; ++kk) {
        int off = kk * 32 + ko;
        short8 ah = *(const short8*)(Arh + off);
        short8 al = *(const short8*)(Arl + off);
        short8 bh = *(const short8*)(Brh + off);
        short8 bl = *(const short8*)(Brl + off);
        a0 = __builtin_amdgcn_mfma_f32_16x16x32_bf16(ah, bh, a0, 0, 0, 0);
        a1 = __builtin_amdgcn_mfma_f32_16x16x32_bf16(al, bh, a1, 0, 0, 0);
        a2 = __builtin_amdgcn_mfma_f32_16x16x32_bf16(ah, bl, a2, 0, 0, 0);
    }
}

// ---------- fused two-layer pipelined LSTM step ----------
// Launch k in [0,513): layer0 computes t0=k (if k<512), layer1 computes t1=k-1 (if k>=1).
// Grid 256 blocks x 256 threads; block = (layer, 32-gate tile); wave = 16 batches x 16 gates.
// Gates in g'=j*4+q order; MFMA 16x16x32, A row = batch (l&15), B row = gate (l&15), k=(l>>4)*8+e.
// No LDS, no barriers. 3 accumulator chains (bf16x3).
__global__ __launch_bounds__(256)
void lstm_fused(int k,
                const ushort_t* __restrict__ ehi,  const ushort_t* __restrict__ elo,
                const ushort_t* __restrict__ wi0h, const ushort_t* __restrict__ wi0l,
                const ushort_t* __restrict__ wh0h, const ushort_t* __restrict__ wh0l,
                const ushort_t* __restrict__ wi1h, const ushort_t* __restrict__ wi1l,
                const ushort_t* __restrict__ wh1h, const ushort_t* __restrict__ wh1l,
                ushort_t* __restrict__ h0hi, ushort_t* __restrict__ h0lo,
                ushort_t* __restrict__ h1hi, ushort_t* __restrict__ h1lo,
                float* __restrict__ c0, float* __restrict__ c1,
                const float* __restrict__ bsum0p, const float* __restrict__ bsum1p)
{
    const int layer = blockIdx.x >> 7;
    if (layer == 0 && k >= NS) return;
    if (layer == 1 && k == 0)  return;
    const int t  = layer ? (k - 1) : k;
    const int nt = blockIdx.x & 127;

    const int tid = threadIdx.x;
    const int l   = tid & 63;
    const int w   = tid >> 6;
    const int wm  = w >> 1, wn = w & 1;

    const int ar   = wm * 16 + (l & 15);          // batch row for A frags
    const int ko   = (l >> 4) * 8;                // k sub-offset
    const int gate = nt * 32 + wn * 16 + (l & 15);// g' for B frags / epilogue col

    f32x4 a0 = {0.f,0.f,0.f,0.f}, a1 = {0.f,0.f,0.f,0.f}, a2 = {0.f,0.f,0.f,0.f};

    if (layer == 0) {
        // recurrent: h0 ring slice prev (slice 2 = zeros at t==0)
        int ps = (t == 0) ? 2 : ((t - 1) & 1);
        const ushort_t* Arh = h0hi + (size_t)ps * NB * HID + (size_t)ar * HID;
        const ushort_t* Arl = h0lo + (size_t)ps * NB * HID + (size_t)ar * HID;
        const ushort_t* Brh = wh0h + (size_t)gate * HID;
        const ushort_t* Brl = wh0l + (size_t)gate * HID;
        mm3<HID/32>(Arh, Arl, Brh, Brl, ko, a0, a1, a2);
        // input: emb slice t
        const ushort_t* Aih = ehi + ((size_t)t * NB + ar) * EMBD;
        const ushort_t* Ail = elo + ((size_t)t * NB + ar) * EMBD;
        const ushort_t* Bih = wi0h + (size_t)gate * EMBD;
        const ushort_t* Bil = wi0l + (size_t)gate * EMBD;
        mm3<EMBD/32>(Aih, Ail, Bih, Bil, ko, a0, a1, a2);
    } else {
        // recurrent: h1 slice t (= time t-1, slices offset by +1)
        const ushort_t* Arh = h1hi + ((size_t)t * NB + ar) * HID;
        const ushort_t* Arl = h1lo + ((size_t)t * NB + ar) * HID;
        const ushort_t* Brh = wh1h + (size_t)gate * HID;
        const ushort_t* Brl = wh1l + (size_t)gate * HID;
        mm3<HID/32>(Arh, Arl, Brh, Brl, ko, a0, a1, a2);
        // input: h0 ring slice for time t
        int is = t & 1;
        const ushort_t* Aih = h0hi + (size_t)is * NB * HID + (size_t)ar * HID;
        const ushort_t* Ail = h0lo + (size_t)is * NB * HID + (size_t)ar * HID;
        const ushort_t* Bih = wi1h + (size_t)gate * HID;
        const ushort_t* Bil = wi1l + (size_t)gate * HID;
        mm3<HID/32>(Aih, Ail, Bih, Bil, ko, a0, a1, a2);
    }

    // gates for this lane: batch = wm*16 + (l>>4)*4 + r, col = gate
    float bias = layer ? bsum1p[gate] : bsum0p[gate];
    float gv[4];
    #pragma unroll
    for (int r = 0; r < 4; ++r) gv[r] = a0[r] + a1[r] + a2[r] + bias;

    // gather i,f,g,o within 4-lane groups (cols = j*4+q consecutive)
    int base = l & ~3;
    float gi[4], gf[4], gg[4], go[4];
    #pragma unroll
    for (int r = 0; r < 4; ++r) {
        gi[r] = __shfl(gv[r], base + 0);
        gf[r] = __shfl(gv[r], base + 1);
        gg[r] = __shfl(gv[r], base + 2);
        go[r] = __shfl(gv[r], base + 3);
    }

    if ((gate & 3) == 0) {
        int j = gate >> 2;
        float* cptr = layer ? c1 : c0;
        ushort_t *Hh, *Hl;
        if (layer == 0) {
            size_t off = (size_t)(t & 1) * NB * HID;
            Hh = h0hi + off; Hl = h0lo + off;
        } else {
            size_t off = (size_t)(t + 1) * NB * HID;
            Hh = h1hi + off; Hl = h1lo + off;
        }
        #pragma unroll
        for (int r = 0; r < 4; ++r) {
            int b = wm * 16 + (l >> 4) * 4 + r;
            float iv = sigm(gi[r]);
            float fv = sigm(gf[r]);
            float gvv = tanhf(gg[r]);
            float ov = sigm(go[r]);
            float cn = fv * cptr[b * HID + j] + iv * gvv;
            cptr[b * HID + j] = cn;
            float h = ov * tanhf(cn);
            ushort_t hh, hl; split2(h, hh, hl);
            Hh[b * HID + j] = hh;
            Hl[b * HID + j] = hl;
        }
    }
}

// ---------- classifier GEMM: out[b*512+t][v] = h1[t*32+b][:] @ clsW[v][:]^T + clsB[v] ----------
// bf16x3, block 128x128 tile, 4 waves each 64x64 (4x4 of 16x16 MFMA tiles), K=1024.
__global__ __launch_bounds__(256)
void gemm_cls(const ushort_t* __restrict__ Ahi, const ushort_t* __restrict__ Alo,
              const ushort_t* __restrict__ Bhi, const ushort_t* __restrict__ Blo,
              const float* __restrict__ bias, float* __restrict__ out)
{
    const int m0 = blockIdx.y * 128, n0 = blockIdx.x * 128;
    const int tid = threadIdx.x, l = tid & 63, w = tid >> 6;
    const int wm = w >> 1, wn = w & 1;
    const int mbase = m0 + wm * 64, nbase = n0 + wn * 64;
    const int ko = (l >> 4) * 8;
    const int lr = l & 15;

    f32x4 acc[4][4];
    #pragma unroll
    for (int i = 0; i < 4; ++i)
        #pragma unroll
        for (int j = 0; j < 4; ++j) acc[i][j] = (f32x4){0.f,0.f,0.f,0.f};

    for (int kk = 0; kk < HID / 32; ++kk) {
        int off = kk * 32 + ko;
        short8 ah[4], al[4], bh[4], bl[4];
        #pragma unroll
        for (int tm = 0; tm < 4; ++tm) {
            size_t row = (size_t)(mbase + tm * 16 + lr) * HID + off;
            ah[tm] = *(const short8*)(Ahi + row);
            al[tm] = *(const short8*)(Alo + row);
        }
        #pragma unroll
        for (int tn = 0; tn < 4; ++tn) {
            size_t row = (size_t)(nbase + tn * 16 + lr) * HID + off;
            bh[tn] = *(const short8*)(Bhi + row);
            bl[tn] = *(const short8*)(Blo + row);
        }
        #pragma unroll
        for (int tm = 0; tm < 4; ++tm)
            #pragma unroll
            for (int tn = 0; tn < 4; ++tn) {
                acc[tm][tn] = __builtin_amdgcn_mfma_f32_16x16x32_bf16(ah[tm], bh[tn], acc[tm][tn], 0,0,0);
                acc[tm][tn] = __builtin_amdgcn_mfma_f32_16x16x32_bf16(al[tm], bh[tn], acc[tm][tn], 0,0,0);
                acc[tm][tn] = __builtin_amdgcn_mfma_f32_16x16x32_bf16(ah[tm], bl[tn], acc[tm][tn], 0,0,0);
            }
    }

    #pragma unroll
    for (int tm = 0; tm < 4; ++tm)
        #pragma unroll
        for (int tn = 0; tn < 4; ++tn) {
            int n = nbase + tn * 16 + lr;
            float bv = bias[n];
            #pragma unroll
            for (int r = 0; r < 4; ++r) {
                int m = mbase + tm * 16 + (l >> 4) * 4 + r;
                int tt = m >> 5, b = m & 31;
                out[((size_t)b * NS + tt) * VOC + n] = acc[tm][tn][r] + bv;
            }
        }
}

extern "C" void kernel_launch(void* const* d_in, const int* in_sizes, int n_in,
                              void* d_out, int out_size, void* d_ws, size_t ws_size,
                              hipStream_t stream)
{
    const int*   x    = (const int*)  d_in[0];
    const float* embW = (const float*)d_in[1];
    const float* embB = (const float*)d_in[2];
    const float* Wih0 = (const float*)d_in[3];
    const float* Whh0 = (const float*)d_in[4];
    const float* bih0 = (const float*)d_in[5];
    const float* bhh0 = (const float*)d_in[6];
    const float* Wih1 = (const float*)d_in[7];
    const float* Whh1 = (const float*)d_in[8];
    const float* bih1 = (const float*)d_in[9];
    const float* bhh1 = (const float*)d_in[10];
    const float* clsW = (const float*)d_in[11];
    const float* clsB = (const float*)d_in[12];
    float* out = (float*)d_out;

    char* p = (char*)d_ws;
    auto alloc = [&](size_t bytes) -> void* {
        void* r = (void*)p; p += (bytes + 255) & ~(size_t)255; return r;
    };
    ushort_t* ehi  = (ushort_t*)alloc((size_t)MROWS * EMBD * 2);
    ushort_t* elo  = (ushort_t*)alloc((size_t)MROWS * EMBD * 2);
    ushort_t* wi0h = (ushort_t*)alloc((size_t)G4 * EMBD * 2);
    ushort_t* wi0l = (ushort_t*)alloc((size_t)G4 * EMBD * 2);
    ushort_t* wh0h = (ushort_t*)alloc((size_t)G4 * HID * 2);
    ushort_t* wh0l = (ushort_t*)alloc((size_t)G4 * HID * 2);
    ushort_t* wi1h = (ushort_t*)alloc((size_t)G4 * HID * 2);
    ushort_t* wi1l = (ushort_t*)alloc((size_t)G4 * HID * 2);
    ushort_t* wh1h = (ushort_t*)alloc((size_t)G4 * HID * 2);
    ushort_t* wh1l = (ushort_t*)alloc((size_t)G4 * HID * 2);
    ushort_t* clsh = (ushort_t*)alloc((size_t)VOC * HID * 2);
    ushort_t* clsl = (ushort_t*)alloc((size_t)VOC * HID * 2);
    ushort_t* h0hi = (ushort_t*)alloc((size_t)3 * NB * HID * 2);     // ring: 0,1 + zero slice 2
    ushort_t* h0lo = (ushort_t*)alloc((size_t)3 * NB * HID * 2);
    ushort_t* h1hi = (ushort_t*)alloc((size_t)(NS + 1) * NB * HID * 2); // slice tt+1 = time tt; slice 0 zeros
    ushort_t* h1lo = (ushort_t*)alloc((size_t)(NS + 1) * NB * HID * 2);
    float*    c0   = (float*)   alloc((size_t)NB * HID * 4);
    float*    c1   = (float*)   alloc((size_t)NB * HID * 4);
    float*    bs0  = (float*)   alloc((size_t)G4 * 4);
    float*    bs1  = (float*)   alloc((size_t)G4 * 4);

    // zero cell states and the zero h-slices (harness poisons ws each call)
    hipMemsetAsync(c0, 0, (size_t)2 * NB * HID * 4, stream);           // c0,c1 contiguous
    hipMemsetAsync(h0hi + (size_t)2 * NB * HID, 0, (size_t)NB * HID * 2, stream);
    hipMemsetAsync(h0lo + (size_t)2 * NB * HID, 0, (size_t)NB * HID * 2, stream);
    hipMemsetAsync(h1hi, 0, (size_t)NB * HID * 2, stream);
    hipMemsetAsync(h1lo, 0, (size_t)NB * HID * 2, stream);

    // weight/bias/emb prep
    wsplit<1><<<(G4 * EMBD) / 256, 256, 0, stream>>>(Wih0, wi0h, wi0l, EMBD);
    wsplit<1><<<(G4 * HID) / 256, 256, 0, stream>>>(Whh0, wh0h, wh0l, HID);
    wsplit<1><<<(G4 * HID) / 256, 256, 0, stream>>>(Wih1, wi1h, wi1l, HID);
    wsplit<1><<<(G4 * HID) / 256, 256, 0, stream>>>(Whh1, wh1h, wh1l, HID);
    wsplit<0><<<(VOC * HID) / 256, 256, 0, stream>>>(clsW, clsh, clsl, HID);
    bias_prep<<<G4 / 256, 256, 0, stream>>>(bih0, bhh0, bih1, bhh1, bs0, bs1);
    embed_split<<<(MROWS * 128) / 256, 256, 0, stream>>>(x, embW, embB, ehi, elo);

    // pipelined scan: 513 launches cover layer0 t=0..511 and layer1 t=0..511
    for (int k = 0; k <= NS; ++k) {
        lstm_fused<<<256, 256, 0, stream>>>(k, ehi, elo,
                                            wi0h, wi0l, wh0h, wh0l,
                                            wi1h, wi1l, wh1h, wh1l,
                                            h0hi, h0lo, h1hi, h1lo,
                                            c0, c1, bs0, bs1);
    }

    // classifier (reads h1 slices 1..512 == rows 0..16383)
    gemm_cls<<<dim3(VOC / 128, MROWS / 128), 256, 0, stream>>>(
        h1hi + (size_t)NB * HID, h1lo + (size_t)NB * HID, clsh, clsl, clsB, out);
}